// Round 10
// baseline (117.182 us; speedup 1.0000x reference)
//
#include <hip/hip_runtime.h>
#include <stdint.h>

#define T_DIM 256
#define K_DIM 3072
#define N_DIM 3072
#define R_DIM 32
#define KG    48      // K / GROUP
#define NSPLIT 4      // gemm k-splits (12 chunks each; last split owns lora tail)

#define PQ_BLOCKS 2304   // pack_qw:   N*K/16 / 256
#define QA_BLOCKS 3072   // quant_act: T*KG waves, 4 waves/block
#define LM_BLOCKS 96     // lora_mid:  K/32

typedef __bf16 bf16x8 __attribute__((ext_vector_type(8)));
typedef float  f32x4  __attribute__((ext_vector_type(4)));
typedef unsigned short u16x8 __attribute__((ext_vector_type(8)));
typedef int    v4i    __attribute__((ext_vector_type(4)));

// round-to-nearest-even fp32 -> bf16 (raw ushort)
__device__ __forceinline__ unsigned short f2bf(float f) {
    unsigned u = __builtin_bit_cast(unsigned, f);
    unsigned rounding = 0x7FFFu + ((u >> 16) & 1u);
    return (unsigned short)((u + rounding) >> 16);
}

__device__ __forceinline__ bf16x8 cvt8(const float* p) {
    float4 lo = ((const float4*)p)[0], hi = ((const float4*)p)[1];
    u16x8 u;
    u[0] = f2bf(lo.x); u[1] = f2bf(lo.y); u[2] = f2bf(lo.z); u[3] = f2bf(lo.w);
    u[4] = f2bf(hi.x); u[5] = f2bf(hi.y); u[6] = f2bf(hi.z); u[7] = f2bf(hi.w);
    return __builtin_bit_cast(bf16x8, u);
}

__device__ __forceinline__ unsigned pack4m8(int4 c) {   // 4 codes -> 4 bytes of (c-8)
    return (unsigned)((c.x - 8) & 255) | ((unsigned)((c.y - 8) & 255) << 8)
         | ((unsigned)((c.z - 8) & 255) << 16) | ((unsigned)((c.w - 8) & 255) << 24);
}

// ---------------- fat prep kernel: pack_qw | quant_act | lora_mid -----------
__global__ __launch_bounds__(256) void prep(
        const int*   __restrict__ qweight,   // [N][K] codes 0..15
        const float* __restrict__ wscales,   // [N][48]
        const float* __restrict__ x,         // [T][K]
        const float* __restrict__ lora_down, // [R][K]
        signed char* __restrict__ Qb,        // [48][N][64] int8 (w-8)
        float*       __restrict__ Sw,        // [48][N] f32
        signed char* __restrict__ Aq,        // [48][256][64] int8 q
        float*       __restrict__ Sa,        // [48][256] f32
        float*       __restrict__ Lm) {      // [T][R] f32 (pre-zeroed)
    int blk = blockIdx.x;
    if (blk < PQ_BLOCKS) {
        // ---- stream qweight once; emit (code-8) int8, chunk-major ----
        size_t i = (size_t)blk * 256 + threadIdx.x;   // over N*K/16
        const int4* p = (const int4*)(qweight + i * 16);
        uint4 w;
        w.x = pack4m8(p[0]); w.y = pack4m8(p[1]);
        w.z = pack4m8(p[2]); w.w = pack4m8(p[3]);
        int n  = (int)(i / 192);        // K/16 units per row
        int kw = (int)(i % 192);
        int kt = kw >> 2;               // 4 units per 64-wide chunk
        int ko = (kw & 3) * 16;
        *(uint4*)(Qb + ((size_t)kt * N_DIM + n) * 64 + ko) = w;
        if ((kw & 3) == 0) Sw[(size_t)kt * N_DIM + n] = wscales[(size_t)n * KG + kt];
    } else if (blk < PQ_BLOCKS + QA_BLOCKS) {
        // ---- per-(token,group) fake-quant -> int8 codes + scale ----
        int widx = (blk - PQ_BLOCKS) * 4 + (threadIdx.x >> 6);   // 0..T*KG-1
        int lane = threadIdx.x & 63;
        int t = widx / KG, g = widx % KG;
        float v = x[(size_t)t * K_DIM + g * 64 + lane];
        float a = fabsf(v);
        #pragma unroll
        for (int off = 32; off; off >>= 1) a = fmaxf(a, __shfl_xor(a, off));
        float scale = fmaxf(a / 7.0f, 1e-8f);
        float q = rintf(v / scale);
        q = fminf(fmaxf(q, -8.f), 7.f);
        Aq[((size_t)g * 256 + t) * 64 + lane] = (signed char)(int)q;
        if (lane == 0) Sa[(size_t)g * 256 + t] = scale;
    } else {
        // ---- lora_mid partial: one 32-wide k-step per block (bf16 MFMA) ----
        int kb = blk - PQ_BLOCKS - QA_BLOCKS;
        int lane = threadIdx.x & 63, wv = threadIdx.x >> 6;
        int mrow = lane & 15, quad = lane >> 4;
        int k0 = kb * 32 + quad * 8;
        bf16x8 a[4], b[2];
        #pragma unroll
        for (int mt = 0; mt < 4; ++mt)
            a[mt] = cvt8(x + (size_t)(wv * 64 + mt * 16 + mrow) * K_DIM + k0);
        #pragma unroll
        for (int nt = 0; nt < 2; ++nt)
            b[nt] = cvt8(lora_down + (size_t)(nt * 16 + mrow) * K_DIM + k0);
        f32x4 acc[4][2];
        f32x4 zero = {0.f, 0.f, 0.f, 0.f};
        #pragma unroll
        for (int i = 0; i < 4; ++i) { acc[i][0] = zero; acc[i][1] = zero; }
        #pragma unroll
        for (int mt = 0; mt < 4; ++mt)
            #pragma unroll
            for (int nt = 0; nt < 2; ++nt)
                acc[mt][nt] = __builtin_amdgcn_mfma_f32_16x16x32_bf16(
                    a[mt], b[nt], acc[mt][nt], 0, 0, 0);
        #pragma unroll
        for (int mt = 0; mt < 4; ++mt)
            #pragma unroll
            for (int nt = 0; nt < 2; ++nt)
                #pragma unroll
                for (int r = 0; r < 4; ++r)
                    atomicAdd(&Lm[(size_t)(wv * 64 + mt * 16 + quad * 4 + r) * R_DIM
                                  + nt * 16 + mrow], acc[mt][nt][r]);
    }
}

// ---------------- gemm v3: i8 MFMA (K=64=GROUP), no LDS, no barriers --------
// grid (48 nblk, 2 mblk, NSPLIT). M-tile 128, N-tile 64, chunk = one group.
// Exact int8x int8 dot per group, scaled in fp32: acc += s_a * s_w * dot_int.
__global__ __launch_bounds__(256) void gemm_main(
        const signed char* __restrict__ Aq,   // [48][256][64] int8
        const signed char* __restrict__ Qb,   // [48][N][64] int8 (w-8)
        const float*       __restrict__ Sa,   // [48][256]
        const float*       __restrict__ Sw,   // [48][N]
        const float*       __restrict__ Lm,   // [T][32] f32
        const float*       __restrict__ lora_up, // [N][32] f32
        float*             __restrict__ P) {  // [NSPLIT][T][N] f32 partials
    int nblk  = blockIdx.x;          // 0..47
    int mblk  = blockIdx.y;          // 0..1
    int split = blockIdx.z;          // 0..NSPLIT-1
    int c0 = split * (KG / NSPLIT);
    int tid = threadIdx.x;
    int lane = tid & 63, wv = tid >> 6;
    int mrow = lane & 15, quad = lane >> 4;
    const int nbase = nblk * 64;
    const int mbase = mblk * 128 + wv * 32;

    f32x4 acc[2][4];
    f32x4 fzero = {0.f, 0.f, 0.f, 0.f};
    #pragma unroll
    for (int i = 0; i < 2; ++i)
        #pragma unroll
        for (int j = 0; j < 4; ++j) acc[i][j] = fzero;

    #pragma unroll 3
    for (int kk = c0; kk < c0 + KG / NSPLIT; ++kk) {
        const signed char* aB = Aq + (size_t)kk * (256 * 64);
        const signed char* bB = Qb + (size_t)kk * ((size_t)N_DIM * 64);
        v4i a[2], b[4];
        #pragma unroll
        for (int mt = 0; mt < 2; ++mt)
            a[mt] = *(const v4i*)(aB + (size_t)(mbase + mt * 16 + mrow) * 64 + quad * 16);
        #pragma unroll
        for (int nt = 0; nt < 4; ++nt)
            b[nt] = *(const v4i*)(bB + (size_t)(nbase + nt * 16 + mrow) * 64 + quad * 16);
        float4 sa[2];
        #pragma unroll
        for (int mt = 0; mt < 2; ++mt)
            sa[mt] = *(const float4*)(Sa + (size_t)kk * 256 + mbase + mt * 16 + quad * 4);
        float sw[4];
        #pragma unroll
        for (int nt = 0; nt < 4; ++nt)
            sw[nt] = Sw[(size_t)kk * N_DIM + nbase + nt * 16 + mrow];
        #pragma unroll
        for (int mt = 0; mt < 2; ++mt)
            #pragma unroll
            for (int nt = 0; nt < 4; ++nt) {
                v4i z = {0, 0, 0, 0};
                v4i d = __builtin_amdgcn_mfma_i32_16x16x64_i8(a[mt], b[nt], z, 0, 0, 0);
                acc[mt][nt][0] += (float)d[0] * (sa[mt].x * sw[nt]);
                acc[mt][nt][1] += (float)d[1] * (sa[mt].y * sw[nt]);
                acc[mt][nt][2] += (float)d[2] * (sa[mt].z * sw[nt]);
                acc[mt][nt][3] += (float)d[3] * (sa[mt].w * sw[nt]);
            }
    }

    // lora tail (last split): K=32=R_DIM bf16 MFMA straight into fp32 acc
    if (split == NSPLIT - 1) {
        bf16x8 at[2], bt[4];
        #pragma unroll
        for (int mt = 0; mt < 2; ++mt)
            at[mt] = cvt8(Lm + (size_t)(mbase + mt * 16 + mrow) * R_DIM + quad * 8);
        #pragma unroll
        for (int nt = 0; nt < 4; ++nt)
            bt[nt] = cvt8(lora_up + (size_t)(nbase + nt * 16 + mrow) * R_DIM + quad * 8);
        #pragma unroll
        for (int mt = 0; mt < 2; ++mt)
            #pragma unroll
            for (int nt = 0; nt < 4; ++nt)
                acc[mt][nt] = __builtin_amdgcn_mfma_f32_16x16x32_bf16(
                    at[mt], bt[nt], acc[mt][nt], 0, 0, 0);
    }

    // epilogue: streamed partial stores
    float* Pp = P + (size_t)split * (T_DIM * N_DIM);
    #pragma unroll
    for (int nt = 0; nt < 4; ++nt) {
        int n = nbase + nt * 16 + mrow;             // C col = lane & 15
        #pragma unroll
        for (int mt = 0; mt < 2; ++mt) {
            int row0 = mblk * 128 + wv * 32 + mt * 16 + quad * 4;
            #pragma unroll
            for (int r = 0; r < 4; ++r)
                Pp[(size_t)(row0 + r) * N_DIM + n] = acc[mt][nt][r];
        }
    }
}

// ---------------- reduce partials + bias -> out -----------------------------
__global__ __launch_bounds__(256) void reduce_out(
        const float4* __restrict__ P, const float* __restrict__ bias,
        float4* __restrict__ out) {
    int i = blockIdx.x * 256 + threadIdx.x;       // over T*N/4
    const int STRIDE = T_DIM * N_DIM / 4;
    float4 bv = *(const float4*)&bias[(i * 4) % N_DIM];
    float4 o = bv;
    #pragma unroll
    for (int s = 0; s < NSPLIT; ++s) {
        float4 v = P[i + s * STRIDE];
        o.x += v.x; o.y += v.y; o.z += v.z; o.w += v.w;
    }
    out[i] = o;
}

extern "C" void kernel_launch(void* const* d_in, const int* in_sizes, int n_in,
                              void* d_out, int out_size, void* d_ws, size_t ws_size,
                              hipStream_t stream) {
    const float* x         = (const float*)d_in[0];
    const int*   qweight   = (const int*)d_in[1];
    const float* wscales   = (const float*)d_in[2];
    const float* lora_down = (const float*)d_in[3];
    const float* lora_up   = (const float*)d_in[4];
    const float* bias      = (const float*)d_in[5];

    char* wsp = (char*)d_ws;
    signed char* Aq = (signed char*)wsp;  wsp += (size_t)KG * 256 * 64;          // 768 KB
    signed char* Qb = (signed char*)wsp;  wsp += (size_t)KG * N_DIM * 64;        // 9.4 MB
    float* Sa = (float*)wsp;              wsp += (size_t)KG * 256 * 4;           // 48 KB
    float* Sw = (float*)wsp;              wsp += (size_t)KG * N_DIM * 4;         // 576 KB
    float* Lm = (float*)wsp;              wsp += (size_t)T_DIM * R_DIM * 4;      // 32 KB
    float* P  = (float*)wsp;                                                     // NSPLIT*3 MB

    hipMemsetAsync(Lm, 0, (size_t)T_DIM * R_DIM * sizeof(float), stream);
    prep<<<PQ_BLOCKS + QA_BLOCKS + LM_BLOCKS, 256, 0, stream>>>(
        qweight, wscales, x, lora_down, Qb, Sw, Aq, Sa, Lm);
    gemm_main<<<dim3(48, 2, NSPLIT), 256, 0, stream>>>(
        Aq, Qb, Sa, Sw, Lm, lora_up, P);
    reduce_out<<<(T_DIM * N_DIM / 4) / 256, 256, 0, stream>>>(
        (const float4*)P, bias, (float4*)d_out);
}